// Round 8
// baseline (181.953 us; speedup 1.0000x reference)
//
#include <hip/hip_runtime.h>
#include <hip/hip_bf16.h>

// Problem dims
#define B_    2
#define CIN   128
#define COUT  128
#define DD    16
#define HH    32
#define WW    32
// out strides: [b][co][d2][h2][w2]
#define OS_H2 64
#define OS_D2 (64*64)
#define OS_CO (32*64*64)
#define OS_B  (COUT*OS_CO)

// phase-pair bf16 arrays (r7-verified):
//   XE[j] = (e_{2j}, e_{2j+1}),  XO[j] = (e_{2j+1}, e_{2j+2})
#define PD_D   18
#define PD_H   34
#define RD     17                      // dwords per row
#define RDB    68                      // bytes per row
#define HWDW   (PD_H*RD)               // 578 dwords per d-plane
#define PLB    (HWDW*4)                // 2312 bytes per d-plane
#define CIW    (PD_D*HWDW)             // 10404 dwords per (b,ci)
#define CIB    (CIW*4)                 // 41616 bytes
#define CI8B   (8*CIB)                 // byte stride for +8 ci
#define ARRD   ((size_t)B_*CIN*CIW)
#define ARRB   (ARRD*4)                // 10,653,696 bytes
#define AFOLD_BYTES (8*32*8*64*16)     // 2 MiB

typedef __attribute__((ext_vector_type(8))) short        short8;
typedef __attribute__((ext_vector_type(4))) float        floatx4;
typedef __attribute__((ext_vector_type(4))) unsigned int uint4v;

static __device__ __forceinline__ unsigned f2bf(float f) {
    union { __hip_bfloat16 h; unsigned short u; } cv;
    cv.h = __float2bfloat16(f);
    return (unsigned)cv.u;
}

// ---------------------------------------------------------------------------
// Kernel 1: fold weights -> per-parity 2x2x2 bf16 kernels, MFMA A order.
// (verified rounds 2-7)
// ---------------------------------------------------------------------------
__global__ __launch_bounds__(256) void fold_kernel(const float* __restrict__ Wk,
                                                   unsigned short* __restrict__ Afold) {
    const int t = blockIdx.x * 256 + threadIdx.x;
    const int p  = t >> 14;
    const int ks = (t >> 9) & 31;
    const int ct = (t >> 6) & 7;
    const int l  = t & 63;
    const int co = ct * 16 + (l & 15);
    const int ci = ks * 4 + (l >> 4);
    const int ed = (p >> 2) & 1, eh = (p >> 1) & 1, ew = p & 1;

    const float* w = Wk + (co * CIN + ci) * 27;
    float wv[27];
    #pragma unroll
    for (int i = 0; i < 27; ++i) wv[i] = w[i];

    short8 pk;
    #pragma unroll
    for (int tt = 0; tt < 8; ++tt) {
        const int td = (tt >> 2) & 1, th = (tt >> 1) & 1, tw = tt & 1;
        const int dlo = ed ? (td ? 2 : 0) : (td ? 1 : 0);
        const int dhi = ed ? (td ? 2 : 1) : (td ? 2 : 0);
        const int hlo = eh ? (th ? 2 : 0) : (th ? 1 : 0);
        const int hhi = eh ? (th ? 2 : 1) : (th ? 2 : 0);
        const int wlo = ew ? (tw ? 2 : 0) : (tw ? 1 : 0);
        const int whi = ew ? (tw ? 2 : 1) : (tw ? 2 : 0);
        float s = 0.f;
        for (int kd = dlo; kd <= dhi; ++kd)
            for (int kh = hlo; kh <= hhi; ++kh)
                for (int kw = wlo; kw <= whi; ++kw)
                    s += wv[kd * 9 + kh * 3 + kw];
        pk[tt] = (short)f2bf(s);
    }
    reinterpret_cast<short8*>(Afold)[t] = pk;
}

// ---------------------------------------------------------------------------
// Kernel 2: convert+pad x -> XE (borders pre-zeroed by memset).
// ---------------------------------------------------------------------------
__global__ __launch_bounds__(256) void pad_kernel(const float* __restrict__ x,
                                                  unsigned* __restrict__ xe) {
    const int idx = blockIdx.x * 256 + threadIdx.x;
    const int w2 = idx & 15;
    const int h  = (idx >> 4) & 31;
    const int d  = (idx >> 9) & 15;
    const int ci = (idx >> 13) & 127;
    const int b  = (idx >> 20) & 1;
    const float2 v = *reinterpret_cast<const float2*>(
        x + (size_t)((b * CIN + ci) * DD + d) * (HH * WW) + h * WW + w2 * 2);
    xe[(size_t)((b * CIN + ci) * PD_D + d + 1) * HWDW
       + (h + 1) * RD + (w2 + 1)] = f2bf(v.x) | (f2bf(v.y) << 16);
}

// ---------------------------------------------------------------------------
// Kernel 3: XO[t] = (XE[t]>>16) | (XE[t+1]<<16)   (r7-verified)
// ---------------------------------------------------------------------------
__global__ __launch_bounds__(256) void xo_kernel(const unsigned* __restrict__ xe,
                                                 unsigned* __restrict__ xo) {
    const size_t t = (size_t)blockIdx.x * 256 + threadIdx.x;
    const unsigned e0 = xe[t];
    const unsigned e1 = (t + 1 < ARRD) ? xe[t + 1] : 0u;
    xo[t] = (e0 >> 16) | (e1 << 16);
}

// ---------------------------------------------------------------------------
// Kernel 4: per-parity implicit GEMM, producer/consumer wave specialization.
//   384 threads: waves 0-3 = compute (A-loads + ds_read + MFMA only),
//                waves 4-5 = producers (gather + ds_write only).
//   One s_barrier per K-chunk (16 each role). Double-buffered B tile.
//   Producer depth-2 register ping-pong -> compiler-counted vmcnt(32).
// ---------------------------------------------------------------------------
__global__ __launch_bounds__(384, 3) void upconv_mfma(
    const char* __restrict__ xe_c, const char* __restrict__ xo_c,
    const unsigned short* __restrict__ Afold,
    const float* __restrict__ bias,
    float* __restrict__ out)
{
    __shared__ short Bt[2][128 * 64];   // 2 x 16 KiB
    char* buf0 = reinterpret_cast<char*>(&Bt[0][0]);
    char* buf1 = reinterpret_cast<char*>(&Bt[1][0]);

    const int tid = threadIdx.x;
    const int d      = blockIdx.x >> 3;
    const int h_base = (blockIdx.x & 7) * 4;
    const int p      = blockIdx.y;
    const int b      = blockIdx.z;
    const int ed = (p >> 2) & 1, eh = (p >> 1) & 1, ew = p & 1;

    if (tid >= 256) {
        // ================= PRODUCERS (2 waves, 128 threads) =================
        const int ptid  = tid - 256;
        const int npair = ptid & 63;
        const int grp   = ptid >> 6;            // 0..1 -> cl = grp*4 + i
        const int hl    = npair >> 4;
        const int s     = npair & 15;
        const int n_a   = hl * 32 + 2 * s;
        const int n_b   = n_a + 1;
        const char* pa = ew ? xe_c : xo_c;
        const char* pb = ew ? xo_c : xe_c;
        const long rowb = ((long)(b * CIN + grp * 4) * PD_D + (d + ed)) * (long)PLB
                        + (long)(h_base + hl + eh) * RDB;
        int offA = (int)rowb + (s + ew) * 4;
        int offB = (int)rowb + (s + 1) * 4;

        int waddr_a[4], waddr_b[4];
        #pragma unroll
        for (int i = 0; i < 4; ++i) {
            const int cl = grp * 4 + i;
            waddr_a[i] = n_a * 128 + ((cl * 16) ^ (((n_a >> 1) & 7) << 4));
            waddr_b[i] = n_b * 128 + ((cl * 16) ^ (((n_b >> 1) & 7) << 4));
        }

        unsigned gaA[4][4], gbA[4][4], gaB[4][4], gbB[4][4];

        #define GATHERP(ga, gb)                                                 \
            do {                                                                \
                _Pragma("unroll")                                               \
                for (int i = 0; i < 4; ++i) {                                   \
                    const char* ba = pa + offA + i * CIB;                       \
                    const char* bb = pb + offB + i * CIB;                       \
                    ga[i][0] = *(const unsigned*)(ba + 0);                      \
                    ga[i][1] = *(const unsigned*)(ba + RDB);                    \
                    ga[i][2] = *(const unsigned*)(ba + PLB);                    \
                    ga[i][3] = *(const unsigned*)(ba + PLB + RDB);              \
                    gb[i][0] = *(const unsigned*)(bb + 0);                      \
                    gb[i][1] = *(const unsigned*)(bb + RDB);                    \
                    gb[i][2] = *(const unsigned*)(bb + PLB);                    \
                    gb[i][3] = *(const unsigned*)(bb + PLB + RDB);              \
                }                                                               \
                offA += CI8B; offB += CI8B;                                     \
            } while (0)

        #define PWRITE(bufc, ga, gb)                                            \
            do {                                                                \
                _Pragma("unroll")                                               \
                for (int i = 0; i < 4; ++i) {                                   \
                    *(uint4v*)(bufc + waddr_a[i]) =                             \
                        (uint4v){ga[i][0], ga[i][1], ga[i][2], ga[i][3]};       \
                    *(uint4v*)(bufc + waddr_b[i]) =                             \
                        (uint4v){gb[i][0], gb[i][1], gb[i][2], gb[i][3]};       \
                }                                                               \
            } while (0)

        GATHERP(gaA, gbA);   // chunk 0
        GATHERP(gaB, gbB);   // chunk 1
        for (int kc = 0; kc < 16; kc += 2) {
            PWRITE(buf0, gaA, gbA);                 // vmcnt(32): waits chunk kc only
            if (kc + 2 < 16) GATHERP(gaA, gbA);     // chunk kc+2
            asm volatile("s_waitcnt lgkmcnt(0)" ::: "memory");
            __builtin_amdgcn_s_barrier();           // barrier kc
            PWRITE(buf1, gaB, gbB);
            if (kc + 3 < 16) GATHERP(gaB, gbB);     // chunk kc+3
            asm volatile("s_waitcnt lgkmcnt(0)" ::: "memory");
            __builtin_amdgcn_s_barrier();           // barrier kc+1
        }
        #undef PWRITE
        #undef GATHERP
        return;
    }

    // =================== CONSUMERS (4 waves, 256 threads) ===================
    const int wave = tid >> 6;
    const int lane = tid & 63;
    const int co0 = (wave >> 1) * 64;
    const int n0  = (wave & 1) * 64;
    const int ct0 = (wave >> 1) * 4;

    int raddr[2][4];
    #pragma unroll
    for (int ksl = 0; ksl < 2; ++ksl)
        #pragma unroll
        for (int nt = 0; nt < 4; ++nt) {
            const int n  = n0 + nt * 16 + (lane & 15);
            const int kb = ksl * 64 + (lane >> 4) * 16;
            raddr[ksl][nt] = n * 128 + (kb ^ (((n >> 1) & 7) << 4));
        }

    floatx4 acc[4][4];
    #pragma unroll
    for (int i = 0; i < 4; ++i)
        #pragma unroll
        for (int j = 0; j < 4; ++j)
            acc[i][j] = (floatx4){0.f, 0.f, 0.f, 0.f};

    const short8* Ap = reinterpret_cast<const short8*>(Afold);

    short8 aC[2][4], aN[2][4];

    #define ALOAD(a, kc)                                                        \
        do {                                                                    \
            _Pragma("unroll")                                                   \
            for (int ksl = 0; ksl < 2; ++ksl)                                   \
                _Pragma("unroll")                                               \
                for (int ct = 0; ct < 4; ++ct)                                  \
                    a[ksl][ct] = Ap[(size_t)(((p) * 32 + (kc) * 2 + ksl) * 8    \
                                             + ct0 + ct) * 64 + lane];          \
        } while (0)

    #define MFMABLOCK(bufc, a)                                                  \
        do {                                                                    \
            __builtin_amdgcn_s_setprio(1);                                      \
            _Pragma("unroll")                                                   \
            for (int ksl = 0; ksl < 2; ++ksl) {                                 \
                short8 bfr[4];                                                  \
                _Pragma("unroll")                                               \
                for (int nt = 0; nt < 4; ++nt)                                  \
                    bfr[nt] = *reinterpret_cast<const short8*>(                 \
                        (bufc) + raddr[ksl][nt]);                               \
                _Pragma("unroll")                                               \
                for (int ct = 0; ct < 4; ++ct)                                  \
                    _Pragma("unroll")                                           \
                    for (int nt = 0; nt < 4; ++nt)                              \
                        acc[ct][nt] = __builtin_amdgcn_mfma_f32_16x16x32_bf16(  \
                            a[ksl][ct], bfr[nt], acc[ct][nt], 0, 0, 0);         \
            }                                                                   \
            __builtin_amdgcn_s_setprio(0);                                      \
        } while (0)

    ALOAD(aC, 0);
    for (int kc = 0; kc < 16; kc += 2) {
        ALOAD(aN, kc + 1);
        __builtin_amdgcn_s_barrier();      // barrier kc: buf0 holds chunk kc
        MFMABLOCK(buf0, aC);
        if (kc + 2 < 16) ALOAD(aC, kc + 2);
        __builtin_amdgcn_s_barrier();      // barrier kc+1: buf1 holds chunk kc+1
        MFMABLOCK(buf1, aN);
    }
    #undef MFMABLOCK
    #undef ALOAD

    // ---- epilogue: add bias, scatter to upsampled layout ----
    float* ob = out + (size_t)b * OS_B + (size_t)(2 * d + ed) * OS_D2;
    #pragma unroll
    for (int ct = 0; ct < 4; ++ct) {
        #pragma unroll
        for (int j = 0; j < 4; ++j) {
            const int co = co0 + ct * 16 + (lane >> 4) * 4 + j;
            const float bv = bias[co];
            #pragma unroll
            for (int nt = 0; nt < 4; ++nt) {
                const int n  = n0 + nt * 16 + (lane & 15);
                const int hh = n >> 5, wl = n & 31;
                const int h2 = 2 * (h_base + hh) + eh;
                const int w2 = 2 * wl + ew;
                ob[(size_t)co * OS_CO + h2 * OS_H2 + w2] = acc[ct][nt][j] + bv;
            }
        }
    }
}

extern "C" void kernel_launch(void* const* d_in, const int* in_sizes, int n_in,
                              void* d_out, int out_size, void* d_ws, size_t ws_size,
                              hipStream_t stream) {
    const float* x    = (const float*)d_in[0];
    const float* Wk   = (const float*)d_in[1];
    const float* bias = (const float*)d_in[2];
    float* out        = (float*)d_out;

    unsigned short* Afold = (unsigned short*)d_ws;
    char* xe = (char*)d_ws + AFOLD_BYTES;
    char* xo = xe + ARRB;

    hipMemsetAsync(xe, 0, ARRB, stream);
    pad_kernel<<<8192, 256, 0, stream>>>(x, (unsigned*)xe);
    xo_kernel<<<(unsigned)(ARRD / 256), 256, 0, stream>>>((const unsigned*)xe,
                                                          (unsigned*)xo);
    fold_kernel<<<512, 256, 0, stream>>>(Wk, Afold);

    dim3 grid(DD * 8, 8, B_);   // (128, 8 parity, 2 batch)
    upconv_mfma<<<grid, 384, 0, stream>>>(xe, xo, Afold, bias, out);
}

// Round 9
// 125.864 us; speedup vs baseline: 1.4456x; 1.4456x over previous
//
#include <hip/hip_runtime.h>
#include <hip/hip_bf16.h>

// Problem dims
#define B_    2
#define CIN   128
#define COUT  128
#define DD    16
#define HH    32
#define WW    32
// out strides: [b][co][d2][h2][w2]
#define OS_H2 64
#define OS_D2 (64*64)
#define OS_CO (32*64*64)
#define OS_B  (COUT*OS_CO)

// phase-pair bf16 arrays (r7-verified):
//   XE[j] = (e_{2j}, e_{2j+1}),  XO[j] = (e_{2j+1}, e_{2j+2})
#define PD_D   18
#define PD_H   34
#define RD     17                      // dwords per row
#define RDB    68                      // bytes per row
#define HWDW   (PD_H*RD)               // 578 dwords per d-plane
#define PLB    (HWDW*4)                // 2312 bytes per d-plane
#define CIW    (PD_D*HWDW)             // 10404 dwords per (b,ci)
#define CIB    (CIW*4)                 // 41616 bytes
#define CI8B   (8*CIB)                 // byte stride for +8 ci
#define ARRD   ((size_t)B_*CIN*CIW)
#define ARRB   (ARRD*4)                // 10,653,696 bytes
#define AFOLD_BYTES (8*32*8*64*16)     // 2 MiB

typedef __attribute__((ext_vector_type(8))) short        short8;
typedef __attribute__((ext_vector_type(4))) float        floatx4;
typedef __attribute__((ext_vector_type(4))) unsigned int uint4v;

static __device__ __forceinline__ unsigned f2bf(float f) {
    union { __hip_bfloat16 h; unsigned short u; } cv;
    cv.h = __float2bfloat16(f);
    return (unsigned)cv.u;
}

// ---------------------------------------------------------------------------
// Kernel 1: fold weights -> per-parity 2x2x2 bf16 kernels, MFMA A order.
// (verified rounds 2-8)
// ---------------------------------------------------------------------------
__global__ __launch_bounds__(256) void fold_kernel(const float* __restrict__ Wk,
                                                   unsigned short* __restrict__ Afold) {
    const int t = blockIdx.x * 256 + threadIdx.x;
    const int p  = t >> 14;
    const int ks = (t >> 9) & 31;
    const int ct = (t >> 6) & 7;
    const int l  = t & 63;
    const int co = ct * 16 + (l & 15);
    const int ci = ks * 4 + (l >> 4);
    const int ed = (p >> 2) & 1, eh = (p >> 1) & 1, ew = p & 1;

    const float* w = Wk + (co * CIN + ci) * 27;
    float wv[27];
    #pragma unroll
    for (int i = 0; i < 27; ++i) wv[i] = w[i];

    short8 pk;
    #pragma unroll
    for (int tt = 0; tt < 8; ++tt) {
        const int td = (tt >> 2) & 1, th = (tt >> 1) & 1, tw = tt & 1;
        const int dlo = ed ? (td ? 2 : 0) : (td ? 1 : 0);
        const int dhi = ed ? (td ? 2 : 1) : (td ? 2 : 0);
        const int hlo = eh ? (th ? 2 : 0) : (th ? 1 : 0);
        const int hhi = eh ? (th ? 2 : 1) : (th ? 2 : 0);
        const int wlo = ew ? (tw ? 2 : 0) : (tw ? 1 : 0);
        const int whi = ew ? (tw ? 2 : 1) : (tw ? 2 : 0);
        float s = 0.f;
        for (int kd = dlo; kd <= dhi; ++kd)
            for (int kh = hlo; kh <= hhi; ++kh)
                for (int kw = wlo; kw <= whi; ++kw)
                    s += wv[kd * 9 + kh * 3 + kw];
        pk[tt] = (short)f2bf(s);
    }
    reinterpret_cast<short8*>(Afold)[t] = pk;
}

// ---------------------------------------------------------------------------
// Kernel 2: convert+pad x -> XE (borders pre-zeroed by memset).
// ---------------------------------------------------------------------------
__global__ __launch_bounds__(256) void pad_kernel(const float* __restrict__ x,
                                                  unsigned* __restrict__ xe) {
    const int idx = blockIdx.x * 256 + threadIdx.x;
    const int w2 = idx & 15;
    const int h  = (idx >> 4) & 31;
    const int d  = (idx >> 9) & 15;
    const int ci = (idx >> 13) & 127;
    const int b  = (idx >> 20) & 1;
    const float2 v = *reinterpret_cast<const float2*>(
        x + (size_t)((b * CIN + ci) * DD + d) * (HH * WW) + h * WW + w2 * 2);
    xe[(size_t)((b * CIN + ci) * PD_D + d + 1) * HWDW
       + (h + 1) * RD + (w2 + 1)] = f2bf(v.x) | (f2bf(v.y) << 16);
}

// ---------------------------------------------------------------------------
// Kernel 3: XO[t] = (XE[t]>>16) | (XE[t+1]<<16)   (r7-verified)
// ---------------------------------------------------------------------------
__global__ __launch_bounds__(256) void xo_kernel(const unsigned* __restrict__ xe,
                                                 unsigned* __restrict__ xo) {
    const size_t t = (size_t)blockIdx.x * 256 + threadIdx.x;
    const unsigned e0 = xe[t];
    const unsigned e1 = (t + 1 < ARRD) ? xe[t + 1] : 0u;
    xo[t] = (e0 >> 16) | (e1 << 16);
}

// ---------------------------------------------------------------------------
// Kernel 4: per-parity implicit GEMM, N-tile = 256 (8 h-rows x 32 w).
//   r7 pipeline: symmetric waves, depth-1 gather prefetch, dbuf LDS,
//   lgkmcnt-only barrier, counted vmcnt (A-loads before gathers).
//   acc[4][8] (128 n per wave), LDS 2 x 32 KiB.
// ---------------------------------------------------------------------------
__global__ __launch_bounds__(256, 2) void upconv_mfma(
    const char* __restrict__ xe_c, const char* __restrict__ xo_c,
    const unsigned short* __restrict__ Afold,
    const float* __restrict__ bias,
    float* __restrict__ out)
{
    __shared__ short Bt[2][256 * 64];   // 2 x 32 KiB
    char* buf0 = reinterpret_cast<char*>(&Bt[0][0]);
    char* buf1 = reinterpret_cast<char*>(&Bt[1][0]);

    const int tid  = threadIdx.x;
    const int wave = tid >> 6;
    const int lane = tid & 63;

    const int d      = blockIdx.x >> 2;          // 0..15
    const int h_base = (blockIdx.x & 3) * 8;     // 0,8,16,24
    const int p      = blockIdx.y;
    const int b      = blockIdx.z;
    const int ed = (p >> 2) & 1, eh = (p >> 1) & 1, ew = p & 1;

    // ---- staging geometry (chunk-invariant) ----
    // thread -> 2 n (w-pair) x 4 ci x 4 taps = 32 dwords per chunk
    const int npair = tid & 127;                 // 128 n-pairs
    const int cig   = tid >> 7;                  // 0..1 -> cl = cig*4 + i
    const int hl    = npair >> 4;                // 0..7
    const int s     = npair & 15;                // w-pair index
    const int n_a   = hl * 32 + 2 * s;
    const int n_b   = n_a + 1;
    // n even: arr = ew?XE:XO, col = s+ew ;  n odd: arr = ew?XO:XE, col = s+1
    const char* pa = ew ? xe_c : xo_c;
    const char* pb = ew ? xo_c : xe_c;
    const long rowb = ((long)(b * CIN + cig * 4) * PD_D + (d + ed)) * (long)PLB
                    + (long)(h_base + hl + eh) * RDB;
    int offA = (int)rowb + (s + ew) * 4;
    int offB = (int)rowb + (s + 1) * 4;

    int waddr_a[4], waddr_b[4];
    #pragma unroll
    for (int i = 0; i < 4; ++i) {
        const int cl = cig * 4 + i;
        waddr_a[i] = n_a * 128 + ((cl * 16) ^ (((n_a >> 1) & 7) << 4));
        waddr_b[i] = n_b * 128 + ((cl * 16) ^ (((n_b >> 1) & 7) << 4));
    }

    // ---- MFMA-read geometry (chunk-invariant; swizzle r5-verified) ----
    const int co0   = (wave >> 1) * 64;
    const int nbase = (wave & 1) * 128;
    const int ct0   = (wave >> 1) * 4;
    int raddr[2][8];
    #pragma unroll
    for (int ksl = 0; ksl < 2; ++ksl)
        #pragma unroll
        for (int nt = 0; nt < 8; ++nt) {
            const int n  = nbase + nt * 16 + (lane & 15);
            const int kb = ksl * 64 + (lane >> 4) * 16;
            raddr[ksl][nt] = n * 128 + (kb ^ (((n >> 1) & 7) << 4));
        }

    floatx4 acc[4][8];
    #pragma unroll
    for (int i = 0; i < 4; ++i)
        #pragma unroll
        for (int j = 0; j < 8; ++j)
            acc[i][j] = (floatx4){0.f, 0.f, 0.f, 0.f};

    const short8* Ap = reinterpret_cast<const short8*>(Afold);

    unsigned ga[4][4], gb[4][4];   // [ci][r]; r offsets {0,68,2312,2380}

    #define GATHER()                                                            \
        do {                                                                    \
            _Pragma("unroll")                                                   \
            for (int i = 0; i < 4; ++i) {                                       \
                const char* ba = pa + offA + i * CIB;                           \
                const char* bb = pb + offB + i * CIB;                           \
                ga[i][0] = *(const unsigned*)(ba + 0);                          \
                ga[i][1] = *(const unsigned*)(ba + RDB);                        \
                ga[i][2] = *(const unsigned*)(ba + PLB);                        \
                ga[i][3] = *(const unsigned*)(ba + PLB + RDB);                  \
                gb[i][0] = *(const unsigned*)(bb + 0);                          \
                gb[i][1] = *(const unsigned*)(bb + RDB);                        \
                gb[i][2] = *(const unsigned*)(bb + PLB);                        \
                gb[i][3] = *(const unsigned*)(bb + PLB + RDB);                  \
            }                                                                   \
            offA += CI8B; offB += CI8B;                                         \
        } while (0)

    #define BODY(kc, bufc, dofill)                                              \
        do {                                                                    \
            short8 a[2][4];                                                     \
            _Pragma("unroll")                                                   \
            for (int ksl = 0; ksl < 2; ++ksl)                                   \
                _Pragma("unroll")                                               \
                for (int ct = 0; ct < 4; ++ct)                                  \
                    a[ksl][ct] = Ap[(size_t)(((p) * 32 + (kc) * 2 + ksl) * 8    \
                                             + ct0 + ct) * 64 + lane];          \
            _Pragma("unroll")                                                   \
            for (int i = 0; i < 4; ++i) {                                       \
                *(uint4v*)(bufc + waddr_a[i]) =                                 \
                    (uint4v){ga[i][0], ga[i][1], ga[i][2], ga[i][3]};           \
                *(uint4v*)(bufc + waddr_b[i]) =                                 \
                    (uint4v){gb[i][0], gb[i][1], gb[i][2], gb[i][3]};           \
            }                                                                   \
            if (dofill) GATHER();                                               \
            asm volatile("s_waitcnt lgkmcnt(0)\n\ts_barrier" ::: "memory");     \
            __builtin_amdgcn_s_setprio(1);                                      \
            _Pragma("unroll")                                                   \
            for (int ksl = 0; ksl < 2; ++ksl) {                                 \
                _Pragma("unroll")                                               \
                for (int nt = 0; nt < 8; ++nt) {                                \
                    const short8 bfr = *reinterpret_cast<const short8*>(        \
                        (bufc) + raddr[ksl][nt]);                               \
                    _Pragma("unroll")                                           \
                    for (int ct = 0; ct < 4; ++ct)                              \
                        acc[ct][nt] = __builtin_amdgcn_mfma_f32_16x16x32_bf16(  \
                            a[ksl][ct], bfr, acc[ct][nt], 0, 0, 0);             \
                }                                                               \
            }                                                                   \
            __builtin_amdgcn_s_setprio(0);                                      \
        } while (0)

    GATHER();
    for (int kc = 0; kc < 16; kc += 2) {
        BODY(kc,     buf0, true);
        BODY(kc + 1, buf1, (kc + 1) != 15);
    }
    #undef BODY
    #undef GATHER

    // ---- epilogue: add bias, scatter to upsampled layout ----
    float* ob = out + (size_t)b * OS_B + (size_t)(2 * d + ed) * OS_D2;
    #pragma unroll
    for (int ct = 0; ct < 4; ++ct) {
        #pragma unroll
        for (int j = 0; j < 4; ++j) {
            const int co = co0 + ct * 16 + (lane >> 4) * 4 + j;
            const float bv = bias[co];
            #pragma unroll
            for (int nt = 0; nt < 8; ++nt) {
                const int n  = nbase + nt * 16 + (lane & 15);
                const int hh = n >> 5, wl = n & 31;
                const int h2 = 2 * (h_base + hh) + eh;
                const int w2 = 2 * wl + ew;
                ob[(size_t)co * OS_CO + h2 * OS_H2 + w2] = acc[ct][nt][j] + bv;
            }
        }
    }
}

extern "C" void kernel_launch(void* const* d_in, const int* in_sizes, int n_in,
                              void* d_out, int out_size, void* d_ws, size_t ws_size,
                              hipStream_t stream) {
    const float* x    = (const float*)d_in[0];
    const float* Wk   = (const float*)d_in[1];
    const float* bias = (const float*)d_in[2];
    float* out        = (float*)d_out;

    unsigned short* Afold = (unsigned short*)d_ws;
    char* xe = (char*)d_ws + AFOLD_BYTES;
    char* xo = xe + ARRB;

    hipMemsetAsync(xe, 0, ARRB, stream);
    pad_kernel<<<8192, 256, 0, stream>>>(x, (unsigned*)xe);
    xo_kernel<<<(unsigned)(ARRD / 256), 256, 0, stream>>>((const unsigned*)xe,
                                                          (unsigned*)xo);
    fold_kernel<<<512, 256, 0, stream>>>(Wk, Afold);

    dim3 grid(DD * 4, 8, B_);   // (64, 8 parity, 2 batch) = 1024 blocks
    upconv_mfma<<<grid, 256, 0, stream>>>(xe, xo, Afold, bias, out);
}